// Round 9
// baseline (148.652 us; speedup 1.0000x reference)
//
#include <hip/hip_runtime.h>
#include <hip/hip_bf16.h>
#include <math.h>

#define NB 16
#define NT 2048
#define ND 512
#define NH 64

typedef __attribute__((ext_vector_type(8))) short short8;
typedef __attribute__((ext_vector_type(4))) float float4v;

__device__ __forceinline__ bool mask_is_bytes(const int* m) {
    return m[0] == 0x01010101;
}
__device__ __forceinline__ bool mask_at(const int* m, bool bytes, int i) {
    if (bytes) return ((const unsigned char*)m)[i] != 0;
    return m[i] != 0;
}

// Minkowski dot, metric folded into `a`; explicit fmaf so pass 1 / pass 2
// recompute bitwise-identical values.
__device__ __forceinline__ float dot4(float4 a, float4 p) {
    float d = a.x * p.x;
    d = __builtin_fmaf(a.y, p.y, d);
    d = __builtin_fmaf(a.z, p.z, d);
    d = __builtin_fmaf(a.w, p.w, d);
    return d;
}

__device__ __forceinline__ unsigned short f2bf(float x) {
    unsigned int u = __float_as_uint(x);
    u += 0x7fffu + ((u >> 16) & 1u);
    return (unsigned short)(u >> 16);
}

// 8-slot sorted-descending insert via med3 chain (reads all OLD regs: ILP-8)
#define INS8(V0,V1,V2,V3,V4,V5,V6,V7,D)                          \
    {                                                            \
        float n0 = fmaxf(V0, D);                                 \
        float n1 = __builtin_amdgcn_fmed3f(D, V0, V1);           \
        float n2 = __builtin_amdgcn_fmed3f(D, V1, V2);           \
        float n3 = __builtin_amdgcn_fmed3f(D, V2, V3);           \
        float n4 = __builtin_amdgcn_fmed3f(D, V3, V4);           \
        float n5 = __builtin_amdgcn_fmed3f(D, V4, V5);           \
        float n6 = __builtin_amdgcn_fmed3f(D, V5, V6);           \
        float n7 = __builtin_amdgcn_fmed3f(D, V6, V7);           \
        V0 = n0; V1 = n1; V2 = n2; V3 = n3;                      \
        V4 = n4; V5 = n5; V6 = n6; V7 = n7;                      \
    }

// ---------------------------------------------------------------------------
// Kernel A: one-time W2 fp32[k][n] -> bf16 W2t[n][k].
// ---------------------------------------------------------------------------
__global__ void __launch_bounds__(256) w2t_kernel(
        const float* __restrict__ W2, unsigned short* __restrict__ W2t) {
    int i = blockIdx.x * 256 + threadIdx.x;
    int n = i & (ND - 1), k = i >> 9;
    W2t[n * NH + k] = f2bf(W2[k * ND + n]);
}

// ---------------------------------------------------------------------------
// Kernel B: fused, 2 TOKENS PER LANE. 512 thr (8 waves), block owns 128
// tokens (lane -> tokens t0+lane and t0+64+lane). Each LDS broadcast read of
// ps now feeds 2 dots -> LDS traffic per token halved vs R8. Grid 256 = 1
// block/CU (LDS ~93 KB). Per-token math bitwise-identical to R8.
// ---------------------------------------------------------------------------
#define VT(w2, j, l)  scratch[((w2) * 8 + (j)) * 128 + (l)]
#define PS(w2, c, l)  scratch[((w2) * 12 + (c)) * 128 + (l)]

__global__ void __launch_bounds__(512) fused_topk_mass_mlp_kernel(
        const float* __restrict__ tok,
        const int* __restrict__ mask,
        const float* __restrict__ W1,
        const float* __restrict__ b1,
        const unsigned short* __restrict__ W2t,
        const float* __restrict__ b2,
        float* __restrict__ out) {
    __shared__ float Plds[NT * 4];            // 32 KB
    __shared__ float scratch[8 * 12 * 128];   // 48 KB (vtop, then psum)
    __shared__ unsigned short hs[64][88];     // 11 KB (reused per half)
    __shared__ float mass_s[3][128];          // 1.5 KB
    __shared__ int wcnt[8];

    const int b    = blockIdx.y;
    const int t0   = blockIdx.x * 128;
    const int tid  = threadIdx.x;
    const int lane = tid & 63;
    const int w    = tid >> 6;
    const bool mb  = mask_is_bytes(mask);

    const bool blockValid = mask_at(mask, mb, b * NT + t0);   // mask monotone

    if (blockValid) {
        // ---- stage tokens -> P in LDS; count L ----
        int cnt = 0;
#pragma unroll
        for (int it = 0; it < 4; ++it) {
            int i = tid + it * 512;
            float4 tv = ((const float4*)tok)[b * NT + i];
            bool m = mask_at(mask, mb, b * NT + i);
            float E = tv.x, Pt = tv.y, eta = tv.z, phi = tv.w;
            float px = Pt * cosf(phi);
            float py = Pt * sinf(phi);
            float pz = Pt * sinhf(fminf(fmaxf(eta, -20.f), 20.f));
            float4 pv = m ? make_float4(E, px, py, pz)
                          : make_float4(-1e30f, 0.f, 0.f, 0.f);
            *(float4*)&Plds[i * 4] = pv;
            cnt += (int)__popcll(__ballot(m));
        }
        if (lane == 0) wcnt[w] = cnt;
        __syncthreads();                               // B1

        int L = 0;
#pragma unroll
        for (int j = 0; j < 8; ++j) L += wcnt[j];
        const int C    = (L + 7) >> 3;
        const int sBeg = w * C;
        const int sEnd = min(sBeg + C, L);

        float4 ptA = *(const float4*)&Plds[(t0 + lane) * 4];
        float4 ptB = *(const float4*)&Plds[(t0 + 64 + lane) * 4];
        float4 aA  = make_float4(ptA.x, -ptA.y, -ptA.z, -ptA.w);
        float4 aB  = make_float4(ptB.x, -ptB.y, -ptB.z, -ptB.w);

        const float NEGBIG = -3.402823466e38f;
        float A0 = NEGBIG, A1 = NEGBIG, A2 = NEGBIG, A3 = NEGBIG;
        float A4 = NEGBIG, A5 = NEGBIG, A6 = NEGBIG, A7 = NEGBIG;
        float B0 = NEGBIG, B1 = NEGBIG, B2 = NEGBIG, B3 = NEGBIG;
        float B4 = NEGBIG, B5 = NEGBIG, B6 = NEGBIG, B7 = NEGBIG;

        // ---- pass 1: chunk-local top-8 for both tokens ----
#pragma unroll 4
        for (int s = sBeg; s < sEnd; ++s) {
            float4 ps = *(const float4*)&Plds[s * 4];   // one read, two dots
            float dA = dot4(aA, ps);
            float dB = dot4(aB, ps);
            INS8(A0, A1, A2, A3, A4, A5, A6, A7, dA);
            INS8(B0, B1, B2, B3, B4, B5, B6, B7, dB);
        }
        VT(w, 0, lane) = A0; VT(w, 1, lane) = A1;
        VT(w, 2, lane) = A2; VT(w, 3, lane) = A3;
        VT(w, 4, lane) = A4; VT(w, 5, lane) = A5;
        VT(w, 6, lane) = A6; VT(w, 7, lane) = A7;
        VT(w, 0, 64 + lane) = B0; VT(w, 1, 64 + lane) = B1;
        VT(w, 2, 64 + lane) = B2; VT(w, 3, 64 + lane) = B3;
        VT(w, 4, 64 + lane) = B4; VT(w, 5, 64 + lane) = B5;
        VT(w, 6, 64 + lane) = B6; VT(w, 7, 64 + lane) = B7;
        __syncthreads();                               // B2

        // ---- merge 64 candidates per token (redundant per wave) ----
        float mA0 = NEGBIG, mA1 = NEGBIG, mA2 = NEGBIG, mA3 = NEGBIG;
        float mA4 = NEGBIG, mA5 = NEGBIG, mA6 = NEGBIG, mA7 = NEGBIG;
        float mB0 = NEGBIG, mB1 = NEGBIG, mB2 = NEGBIG, mB3 = NEGBIG;
        float mB4 = NEGBIG, mB5 = NEGBIG, mB6 = NEGBIG, mB7 = NEGBIG;
#pragma unroll
        for (int w2 = 0; w2 < 8; ++w2) {
#pragma unroll
            for (int j = 0; j < 8; ++j) {
                float dA = VT(w2, j, lane);
                float dB = VT(w2, j, 64 + lane);
                INS8(mA0, mA1, mA2, mA3, mA4, mA5, mA6, mA7, dA);
                INS8(mB0, mB1, mB2, mB3, mB4, mB5, mB6, mB7, dB);
            }
        }
        const float th2A = mA1, th4A = mA3, th8A = mA7;
        const float th2B = mB1, th4B = mB3, th8B = mB7;
        __syncthreads();                               // B3 (vtop dead)

        // ---- pass 2: exact-membership partial sums, both tokens ----
        float a2x = 0.f, a2y = 0.f, a2z = 0.f, a2w = 0.f;
        float a4x = 0.f, a4y = 0.f, a4z = 0.f, a4w = 0.f;
        float a8x = 0.f, a8y = 0.f, a8z = 0.f, a8w = 0.f;
        float b2x = 0.f, b2y = 0.f, b2z = 0.f, b2w = 0.f;
        float b4x = 0.f, b4y = 0.f, b4z = 0.f, b4w = 0.f;
        float b8x = 0.f, b8y = 0.f, b8z = 0.f, b8w = 0.f;
#pragma unroll 4
        for (int s = sBeg; s < sEnd; ++s) {
            float4 ps = *(const float4*)&Plds[s * 4];
            float dA = dot4(aA, ps);
            float dB = dot4(aB, ps);
            if (dA >= th8A) {
                a8x += ps.x; a8y += ps.y; a8z += ps.z; a8w += ps.w;
                if (dA >= th4A) {
                    a4x += ps.x; a4y += ps.y; a4z += ps.z; a4w += ps.w;
                    if (dA >= th2A) {
                        a2x += ps.x; a2y += ps.y; a2z += ps.z; a2w += ps.w;
                    }
                }
            }
            if (dB >= th8B) {
                b8x += ps.x; b8y += ps.y; b8z += ps.z; b8w += ps.w;
                if (dB >= th4B) {
                    b4x += ps.x; b4y += ps.y; b4z += ps.z; b4w += ps.w;
                    if (dB >= th2B) {
                        b2x += ps.x; b2y += ps.y; b2z += ps.z; b2w += ps.w;
                    }
                }
            }
        }
        PS(w, 0, lane) = a2x;  PS(w, 1, lane) = a2y;
        PS(w, 2, lane) = a2z;  PS(w, 3, lane) = a2w;
        PS(w, 4, lane) = a4x;  PS(w, 5, lane) = a4y;
        PS(w, 6, lane) = a4z;  PS(w, 7, lane) = a4w;
        PS(w, 8, lane) = a8x;  PS(w, 9, lane) = a8y;
        PS(w, 10, lane) = a8z; PS(w, 11, lane) = a8w;
        PS(w, 0, 64 + lane) = b2x;  PS(w, 1, 64 + lane) = b2y;
        PS(w, 2, 64 + lane) = b2z;  PS(w, 3, 64 + lane) = b2w;
        PS(w, 4, 64 + lane) = b4x;  PS(w, 5, 64 + lane) = b4y;
        PS(w, 6, 64 + lane) = b4z;  PS(w, 7, 64 + lane) = b4w;
        PS(w, 8, 64 + lane) = b8x;  PS(w, 9, 64 + lane) = b8y;
        PS(w, 10, 64 + lane) = b8z; PS(w, 11, 64 + lane) = b8w;
        __syncthreads();                               // B4

        // ---- waves 0,1: reduce + masses for tokens w*64+lane ----
        if (w < 2) {
            const int tl = w * 64 + lane;
            float tot[12];
#pragma unroll
            for (int c = 0; c < 12; ++c) {
                float acc = 0.f;
#pragma unroll
                for (int w2 = 0; w2 < 8; ++w2) acc += PS(w2, c, tl);
                tot[c] = acc;
            }
            const bool maskt = (t0 + tl) < L;
            const float MZ = sqrtf(1e-8f);
            auto massf = [&](float sx, float sy, float sz, float sw) -> float {
                float q = sx * sx;
                q = __builtin_fmaf(-sy, sy, q);
                q = __builtin_fmaf(-sz, sz, q);
                q = __builtin_fmaf(-sw, sw, q);
                q = fmaxf(q, 0.f);
                return sqrtf(q + 1e-8f);
            };
            mass_s[0][tl] = maskt ? massf(tot[0], tot[1], tot[2], tot[3]) : MZ;
            mass_s[1][tl] = maskt ? massf(tot[4], tot[5], tot[6], tot[7]) : MZ;
            mass_s[2][tl] = maskt ? massf(tot[8], tot[9], tot[10], tot[11]) : MZ;
        }
    } else {
        if (tid < 128) {
            const float MZ = sqrtf(1e-8f);
            mass_s[0][tid] = MZ;
            mass_s[1][tid] = MZ;
            mass_s[2][tid] = MZ;
        }
    }
    __syncthreads();                                   // B5 (common)

    // ---- epilogue: two 64-token halves through the proven MFMA block ----
    const int col   = lane & 15;
    const int quad  = lane >> 4;
    const int mhalf = w >> 2;
    const int nBase = (w & 3) * 128;

#pragma unroll
    for (int half = 0; half < 2; ++half) {
        // h = gelu(mass @ W1 + b1) for tokens t0 + half*64 .. +63
        {
            const int tt = lane;
            const int hr = w;              // wave-uniform -> W1/b1 scalar loads
            float q0 = mass_s[0][half * 64 + tt];
            float q1 = mass_s[1][half * 64 + tt];
            float q2 = mass_s[2][half * 64 + tt];
            unsigned short hv[8];
#pragma unroll
            for (int j = 0; j < 8; ++j) {
                int hh = hr * 8 + j;
                float pre = b1[hh];
                pre = __builtin_fmaf(q0, W1[hh], pre);
                pre = __builtin_fmaf(q1, W1[NH + hh], pre);
                pre = __builtin_fmaf(q2, W1[2 * NH + hh], pre);
                float g = 0.5f * pre * (1.0f + erff(pre * 0.70710678118654752f));
                hv[j] = f2bf(g);
            }
            *(short8*)&hs[tt][hr * 8] = *(const short8*)hv;
        }
        __syncthreads();

        short8 afrag[2][2];
#pragma unroll
        for (int mt = 0; mt < 2; ++mt)
#pragma unroll
            for (int ks = 0; ks < 2; ++ks)
                afrag[mt][ks] = *(const short8*)&hs[mhalf * 32 + mt * 16 + col][ks * 32 + quad * 8];

        float4v acc[2][8];
#pragma unroll
        for (int mt = 0; mt < 2; ++mt)
#pragma unroll
            for (int nt = 0; nt < 8; ++nt)
                acc[mt][nt] = (float4v)(0.f);

#pragma unroll
        for (int nt = 0; nt < 8; ++nt) {
            const unsigned short* wp = W2t + (nBase + nt * 16 + col) * NH + quad * 8;
            short8 bf0 = *(const short8*)(wp);
            short8 bf1 = *(const short8*)(wp + 32);
            acc[0][nt] = __builtin_amdgcn_mfma_f32_16x16x32_bf16(afrag[0][0], bf0, acc[0][nt], 0, 0, 0);
            acc[1][nt] = __builtin_amdgcn_mfma_f32_16x16x32_bf16(afrag[1][0], bf0, acc[1][nt], 0, 0, 0);
            acc[0][nt] = __builtin_amdgcn_mfma_f32_16x16x32_bf16(afrag[0][1], bf1, acc[0][nt], 0, 0, 0);
            acc[1][nt] = __builtin_amdgcn_mfma_f32_16x16x32_bf16(afrag[1][1], bf1, acc[1][nt], 0, 0, 0);
        }

#pragma unroll
        for (int nt = 0; nt < 8; ++nt) {
            float bias = b2[nBase + nt * 16 + col];
#pragma unroll
            for (int mt = 0; mt < 2; ++mt) {
                int mRow = b * NT + t0 + half * 64 + mhalf * 32 + mt * 16 + quad * 4;
                size_t base = (size_t)mRow * ND + nBase + nt * 16 + col;
#pragma unroll
                for (int r = 0; r < 4; ++r) {
                    out[base + (size_t)r * ND] = acc[mt][nt][r] + bias;
                }
            }
        }
        __syncthreads();   // hs reused by next half (harmless on last iter)
    }
}

extern "C" void kernel_launch(void* const* d_in, const int* in_sizes, int n_in,
                              void* d_out, int out_size, void* d_ws, size_t ws_size,
                              hipStream_t stream) {
    const float* tok  = (const float*)d_in[0];
    const int*   mask = (const int*)d_in[1];   // layout auto-detected in-kernel
    const float* W1   = (const float*)d_in[2];
    const float* b1   = (const float*)d_in[3];
    const float* W2   = (const float*)d_in[4];
    const float* b2   = (const float*)d_in[5];
    float*       out  = (float*)d_out;

    unsigned short* W2t = (unsigned short*)d_ws;       // 64 KB

    w2t_kernel<<<dim3(ND * NH / 256), dim3(256), 0, stream>>>(W2, W2t);

    dim3 gB(NT / 128, NB);
    fused_topk_mass_mlp_kernel<<<gB, dim3(512), 0, stream>>>(
        tok, mask, W1, b1, W2t, b2, out);
}